// Round 4
// baseline (448.827 us; speedup 1.0000x reference)
//
#include <hip/hip_runtime.h>
#include <hip/hip_bf16.h>

#define B_DIM   16384
#define D_IN    1024
#define D_EXP   1024
#define D_TOW   512
#define N_EXPT  8
#define N_TASK  4

typedef _Float16 f16x8 __attribute__((ext_vector_type(8)));
typedef _Float16 f16x4 __attribute__((ext_vector_type(4)));
typedef float    f32x4 __attribute__((ext_vector_type(4)));

// ---------------- async global->LDS (16B per lane, wave-uniform LDS base) ---
__device__ __forceinline__ void gll16(const void* g, void* l) {
  __builtin_amdgcn_global_load_lds(
      (const __attribute__((address_space(1))) unsigned int*)g,
      (__attribute__((address_space(3))) unsigned int*)l,
      16, 0, 0);
}

// Fragment read from a swizzled [128][64] f16 LDS half-tile.
// 16B chunk s within a 128B row holds global chunk s^(row&7).
__device__ __forceinline__ f16x8 ldfrag(const _Float16* sM, int rowbase, int ks, int lane) {
  int rl = rowbase + (lane & 15);
  int ch = ((ks << 2) + (lane >> 4)) ^ (rl & 7);
  return *(const f16x8*)&sM[rl * 64 + ch * 8];
}

// ---------------- prep: x -> f16, gates = x @ gate_w (fp32) ----------------
__global__ __launch_bounds__(256) void prep_x_kernel(
    const float* __restrict__ x, const float* __restrict__ gw,
    _Float16* __restrict__ xh, float* __restrict__ gates)
{
  __shared__ float sred[4][8];
  const int t = threadIdx.x;
  const long row = blockIdx.x;
  float4 v = ((const float4*)(x + row * D_IN))[t];
  f16x4 h;
  h[0] = (_Float16)v.x; h[1] = (_Float16)v.y; h[2] = (_Float16)v.z; h[3] = (_Float16)v.w;
  ((f16x4*)(xh + row * D_IN))[t] = h;

  float g[8];
#pragma unroll
  for (int e = 0; e < 8; ++e) g[e] = 0.f;
  const float* wp = gw + (size_t)t * 4 * 8;
  float xs[4] = {v.x, v.y, v.z, v.w};
#pragma unroll
  for (int j = 0; j < 4; ++j)
#pragma unroll
    for (int e = 0; e < 8; ++e) g[e] += xs[j] * wp[j * 8 + e];

#pragma unroll
  for (int e = 0; e < 8; ++e) {
    g[e] += __shfl_xor(g[e], 1);  g[e] += __shfl_xor(g[e], 2);
    g[e] += __shfl_xor(g[e], 4);  g[e] += __shfl_xor(g[e], 8);
    g[e] += __shfl_xor(g[e], 16); g[e] += __shfl_xor(g[e], 32);
  }
  if ((t & 63) == 0) {
#pragma unroll
    for (int e = 0; e < 8; ++e) sred[t >> 6][e] = g[e];
  }
  __syncthreads();
  if (t < 8) gates[row * 8 + t] = sred[0][t] + sred[1][t] + sred[2][t] + sred[3][t];
}

// ---------------- tiled transpose + fp32->f16: in[s][K][N] -> out[s][N][K] --
__global__ __launch_bounds__(256) void transpose_cvt_kernel(
    const float* __restrict__ in, _Float16* __restrict__ outp, int K, int N)
{
  __shared__ float tile[64][65];
  const int t = threadIdx.x;
  const int tx = t & 63, ty = t >> 6;
  const int n0 = blockIdx.x * 64;
  const int k0 = blockIdx.y * 64;
  const long s = blockIdx.z;
  const float* ip = in + s * (long)K * N;
  _Float16* op = outp + s * (long)K * N;
#pragma unroll
  for (int i = 0; i < 16; ++i) {
    int r = ty * 16 + i;
    tile[r][tx] = ip[(long)(k0 + r) * N + n0 + tx];
  }
  __syncthreads();
#pragma unroll
  for (int i = 0; i < 16; ++i) {
    int r = ty * 16 + i;
    op[(long)(n0 + r) * K + k0 + tx] = (_Float16)tile[tx][r];
  }
}

// ---------------- init d_out with tb2 --------------------------------------
__global__ void init_out_kernel(float* __restrict__ out, const float* __restrict__ tb2) {
  int i = blockIdx.x * 256 + threadIdx.x;
  if (i < N_TASK * B_DIM) out[i] = tb2[i >> 14];
}

// ============ m201-geometry phase macro =====================================
// BM=256, BN=256, BK=64; 8 waves 2M x 4N; per-wave C = 128x64.
// LDS slot (64KB): A-half0 [128x64]@0, A-half1 @8192, B-half0 @16384,
// B-half1 @24576 (f16 idx). Phase Q computes mf-quadrant {2Q,2Q+1} x all nf.
// bf (full K-tile) loaded at Q==0. One half-tile stage (2 gll16) per phase.
#define PH(SLOT, Q, STAGES, WAITS)                                             \
  do {                                                                         \
    const _Float16* sAq = &sT[SLOT][wm * 8192];                                \
    const _Float16* sBq = &sT[SLOT][16384 + (wn >> 1) * 8192];                 \
    f16x8 af[2][2];                                                            \
    _Pragma("unroll") for (int m2 = 0; m2 < 2; ++m2)                           \
      _Pragma("unroll") for (int ks = 0; ks < 2; ++ks)                         \
        af[m2][ks] = ldfrag(sAq, ((Q) * 2 + m2) * 16, ks, lane);               \
    if ((Q) == 0) {                                                            \
      _Pragma("unroll") for (int nf = 0; nf < 4; ++nf)                         \
        _Pragma("unroll") for (int ks = 0; ks < 2; ++ks)                       \
          bf[nf][ks] = ldfrag(sBq, (wn & 1) * 64 + nf * 16, ks, lane);         \
    }                                                                          \
    STAGES;                                                                    \
    asm volatile("" ::: "memory");                                             \
    if ((Q) == 0) { asm volatile("s_waitcnt lgkmcnt(8)" ::: "memory"); }       \
    __builtin_amdgcn_s_barrier();                                              \
    asm volatile("s_waitcnt lgkmcnt(0)" ::: "memory");                         \
    __builtin_amdgcn_sched_barrier(0);                                         \
    __builtin_amdgcn_s_setprio(1);                                             \
    _Pragma("unroll") for (int m2 = 0; m2 < 2; ++m2)                           \
      _Pragma("unroll") for (int nf = 0; nf < 4; ++nf)                         \
        _Pragma("unroll") for (int ks = 0; ks < 2; ++ks)                       \
          acc[(Q) * 2 + m2][nf] = __builtin_amdgcn_mfma_f32_16x16x32_f16(      \
              af[m2][ks], bf[nf][ks], acc[(Q) * 2 + m2][nf], 0, 0, 0);         \
    __builtin_amdgcn_s_setprio(0);                                             \
    WAITS;                                                                     \
    asm volatile("" ::: "memory");                                             \
    __builtin_amdgcn_s_barrier();                                              \
  } while (0)

// ---------------- fused experts + gate-weighted combine ---------------------
// shared[b,d] = sum_e gates[b,e] * relu(x[b,:] @ exp_w[e,:,d] + exp_b[e,d])
__global__ __launch_bounds__(512, 2) void moe_expert_kernel(
    const _Float16* __restrict__ xh,    // [B,1024]
    const _Float16* __restrict__ ewT,   // [8][n=1024][k=1024]
    const float* __restrict__ expb,     // [8][1024]
    const float* __restrict__ gates,    // [B][8]
    _Float16* __restrict__ shout)       // [B,1024] f16
{
  __shared__ alignas(16) _Float16 sT[2][32768];   // 128KB
  __shared__ float sG[256 * 8];                   // 8KB
  __shared__ float sBias[8 * 256];                // 8KB
  const int t = threadIdx.x;
  const int lane = t & 63;
  const int wave = t >> 6;
  const int wm = wave >> 2, wn = wave & 3;
  const long row0 = (long)blockIdx.x * 256;
  const int col0 = blockIdx.y * 256;

  for (int i = t; i < 256 * 8; i += 512) sG[i] = gates[row0 * 8 + i];
  for (int i = t; i < 8 * 256; i += 512)
    sBias[i] = expb[(i >> 8) * D_EXP + col0 + (i & 255)];

  const int so_t = (((t & 7) ^ ((t >> 3) & 7)) << 4);
  const char* aBase = (const char*)xh + row0 * 2048 + (size_t)(t >> 3) * 2048 + so_t;
  const char* bRoot = (const char*)ewT + (size_t)col0 * 2048 + (size_t)(t >> 3) * 2048 + so_t;
  char* sTB = (char*)&sT[0][0];

  // A half h: 128 rows x 64 k (16KB); B half h: 128 n-rows x 64 k
  auto SA = [&](int s, int h, int kt) {
    const char* g = aBase + (size_t)h * 262144 + (size_t)(kt & 15) * 128;
    char* d = sTB + s * 65536 + h * 16384 + t * 16;
    gll16(g, d); gll16(g + 131072, d + 8192);
    asm volatile("" ::: "memory");
  };
  auto SB = [&](int s, int h, int kt) {
    const char* g = bRoot + (size_t)(kt >> 4) * 2097152 + (size_t)h * 262144
                    + (size_t)(kt & 15) * 128;
    char* d = sTB + s * 65536 + 32768 + h * 16384 + t * 16;
    gll16(g, d); gll16(g + 131072, d + 8192);
    asm volatile("" ::: "memory");
  };

  __syncthreads();   // sG/sBias visible; vmcnt fully drained -> clean FIFO

  // prologue: s0.B, s0.A (kt=0), s1.B (kt=1); s1.A staged at P1,P2 of iter 0
  SB(0, 0, 0); SB(0, 1, 0);
  SA(0, 0, 0); SA(0, 1, 0);
  SB(1, 0, 1); SB(1, 1, 1);
  asm volatile("s_waitcnt vmcnt(4)" ::: "memory");
  __builtin_amdgcn_s_barrier();

  f32x4 acc[8][4] = {};
  f16x4 shacc[8][4] = {};
  f16x8 bf[4][2];

  for (int it = 0; it < 64; ++it) {
    const int kt0 = 2 * it, kt1 = 2 * it + 1;
    const bool pf = (it < 63);

    PH(0, 0, { SA(1, 0, kt1); }, {});
    PH(0, 1, { SA(1, 1, kt1); }, {});
    PH(0, 2, { if (pf) SB(0, 0, kt0 + 2); }, {});
    PH(0, 3, { if (pf) SB(0, 1, kt0 + 2); },
       { if (pf) { asm volatile("s_waitcnt vmcnt(4)" ::: "memory"); }
         else    { asm volatile("s_waitcnt vmcnt(0)" ::: "memory"); } });
    PH(1, 0, { if (pf) SA(0, 0, kt0 + 2); }, {});
    PH(1, 1, { if (pf) SA(0, 1, kt0 + 2); }, {});
    PH(1, 2, { if (pf) SB(1, 0, kt1 + 2); }, {});
    PH(1, 3, { if (pf) SB(1, 1, kt1 + 2); },
       { if (pf) { asm volatile("s_waitcnt vmcnt(4)" ::: "memory"); } });

    if ((it & 7) == 7) {
      const int e = it >> 3;
      float bias4[4];
#pragma unroll
      for (int nf = 0; nf < 4; ++nf)
        bias4[nf] = sBias[e * 256 + wn * 64 + nf * 16 + (lane & 15)];
#pragma unroll
      for (int mf = 0; mf < 8; ++mf) {
        int rbase = wm * 128 + mf * 16 + ((lane >> 4) << 2);
        float gv[4];
#pragma unroll
        for (int r = 0; r < 4; ++r) gv[r] = sG[(rbase + r) * 8 + e];
#pragma unroll
        for (int nf = 0; nf < 4; ++nf) {
          f16x4 sh = shacc[mf][nf];
#pragma unroll
          for (int r = 0; r < 4; ++r) {
            float hv = acc[mf][nf][r] + bias4[nf];
            hv = hv > 0.f ? hv : 0.f;
            sh[r] += (_Float16)(gv[r] * hv);
          }
          shacc[mf][nf] = sh;
          acc[mf][nf] = f32x4{0.f, 0.f, 0.f, 0.f};
        }
      }
    }
  }

  // write shared tile as f16
#pragma unroll
  for (int mf = 0; mf < 8; ++mf)
#pragma unroll
    for (int r = 0; r < 4; ++r) {
      long row = row0 + wm * 128 + mf * 16 + ((lane >> 4) << 2) + r;
      _Float16* op = shout + row * D_EXP + col0 + wn * 64 + (lane & 15);
#pragma unroll
      for (int nf = 0; nf < 4; ++nf) op[nf * 16] = shacc[mf][nf][r];
    }
}

// ---------------- fused towers ----------------------------------------------
// out[task,b] += sum_h relu(shared[b,:] @ tw1[task,:,h] + tb1[task,h]) * tw2[task,h]
__global__ __launch_bounds__(512, 2) void moe_tower_kernel(
    const _Float16* __restrict__ sh,    // [B,1024] f16
    const _Float16* __restrict__ t1T,   // [4][h=512][d=1024] f16
    const float* __restrict__ tb1,      // [4][512]
    const float* __restrict__ tw2,      // [4][512]
    float* __restrict__ out)            // [4][B]
{
  __shared__ alignas(16) _Float16 sT[2][32768];   // 128KB
  const int t = threadIdx.x;
  const int lane = t & 63;
  const int wave = t >> 6;
  const int wm = wave >> 2, wn = wave & 3;
  const long row0 = (long)blockIdx.x * 256;
  const int task = blockIdx.y >> 1;
  const int col0 = (blockIdx.y & 1) * 256;

  float b1[4], w2[4];
#pragma unroll
  for (int nf = 0; nf < 4; ++nf) {
    int col = col0 + wn * 64 + nf * 16 + (lane & 15);
    b1[nf] = tb1[task * D_TOW + col];
    w2[nf] = tw2[task * D_TOW + col];
  }
  asm volatile("s_waitcnt vmcnt(0)" ::: "memory");  // clean FIFO before staging

  const int so_t = (((t & 7) ^ ((t >> 3) & 7)) << 4);
  const char* aBase = (const char*)sh + row0 * 2048 + (size_t)(t >> 3) * 2048 + so_t;
  const char* bRoot = (const char*)t1T + (size_t)task * (D_TOW * D_EXP * 2)
                      + (size_t)col0 * 2048 + (size_t)(t >> 3) * 2048 + so_t;
  char* sTB = (char*)&sT[0][0];

  auto SA = [&](int s, int h, int kt) {
    const char* g = aBase + (size_t)h * 262144 + (size_t)kt * 128;
    char* d = sTB + s * 65536 + h * 16384 + t * 16;
    gll16(g, d); gll16(g + 131072, d + 8192);
    asm volatile("" ::: "memory");
  };
  auto SB = [&](int s, int h, int kt) {
    const char* g = bRoot + (size_t)h * 262144 + (size_t)kt * 128;
    char* d = sTB + s * 65536 + 32768 + h * 16384 + t * 16;
    gll16(g, d); gll16(g + 131072, d + 8192);
    asm volatile("" ::: "memory");
  };

  __syncthreads();

  SB(0, 0, 0); SB(0, 1, 0);
  SA(0, 0, 0); SA(0, 1, 0);
  SB(1, 0, 1); SB(1, 1, 1);
  asm volatile("s_waitcnt vmcnt(4)" ::: "memory");
  __builtin_amdgcn_s_barrier();

  f32x4 acc[8][4] = {};
  f16x8 bf[4][2];

  for (int it = 0; it < 8; ++it) {
    const int kt0 = 2 * it, kt1 = 2 * it + 1;
    const bool pf = (it < 7);

    PH(0, 0, { SA(1, 0, kt1); }, {});
    PH(0, 1, { SA(1, 1, kt1); }, {});
    PH(0, 2, { if (pf) SB(0, 0, kt0 + 2); }, {});
    PH(0, 3, { if (pf) SB(0, 1, kt0 + 2); },
       { if (pf) { asm volatile("s_waitcnt vmcnt(4)" ::: "memory"); }
         else    { asm volatile("s_waitcnt vmcnt(0)" ::: "memory"); } });
    PH(1, 0, { if (pf) SA(0, 0, kt0 + 2); }, {});
    PH(1, 1, { if (pf) SA(0, 1, kt0 + 2); }, {});
    PH(1, 2, { if (pf) SB(1, 0, kt1 + 2); }, {});
    PH(1, 3, { if (pf) SB(1, 1, kt1 + 2); },
       { if (pf) { asm volatile("s_waitcnt vmcnt(4)" ::: "memory"); } });
  }

#pragma unroll
  for (int mf = 0; mf < 8; ++mf)
#pragma unroll
    for (int r = 0; r < 4; ++r) {
      float ssum = 0.f;
#pragma unroll
      for (int nf = 0; nf < 4; ++nf) {
        float v = acc[mf][nf][r] + b1[nf];
        v = v > 0.f ? v : 0.f;
        ssum += v * w2[nf];
      }
      ssum += __shfl_xor(ssum, 1);
      ssum += __shfl_xor(ssum, 2);
      ssum += __shfl_xor(ssum, 4);
      ssum += __shfl_xor(ssum, 8);
      if ((lane & 15) == 0) {
        long row = row0 + wm * 128 + mf * 16 + ((lane >> 4) << 2) + r;
        atomicAdd(&out[(size_t)task * B_DIM + row], ssum);
      }
    }
}

// ---------------- launch -----------------------------------------------------
extern "C" void kernel_launch(void* const* d_in, const int* in_sizes, int n_in,
                              void* d_out, int out_size, void* d_ws, size_t ws_size,
                              hipStream_t stream) {
  const float* x    = (const float*)d_in[0];
  const float* gw   = (const float*)d_in[1];
  const float* expw = (const float*)d_in[2];
  const float* expb = (const float*)d_in[3];
  const float* tw1  = (const float*)d_in[4];
  const float* tb1  = (const float*)d_in[5];
  const float* tw2  = (const float*)d_in[6];
  const float* tb2  = (const float*)d_in[7];
  float* out = (float*)d_out;

  char* ws = (char*)d_ws;
  _Float16* xh  = (_Float16*)ws;  ws += (size_t)B_DIM * D_IN * 2;          // 32 MB
  _Float16* ewT = (_Float16*)ws;  ws += (size_t)N_EXPT * D_IN * D_EXP * 2; // 16 MB
  _Float16* t1T = (_Float16*)ws;  ws += (size_t)N_TASK * D_TOW * D_EXP * 2; // 4 MB
  _Float16* shh = (_Float16*)ws;  ws += (size_t)B_DIM * D_EXP * 2;         // 32 MB
  float* gates  = (float*)ws;     ws += (size_t)B_DIM * N_EXPT * 4;        // 0.5 MB

  prep_x_kernel<<<B_DIM, 256, 0, stream>>>(x, gw, xh, gates);
  transpose_cvt_kernel<<<dim3(D_EXP / 64, D_IN / 64, N_EXPT), 256, 0, stream>>>(
      expw, ewT, D_IN, D_EXP);
  transpose_cvt_kernel<<<dim3(D_TOW / 64, D_EXP / 64, N_TASK), 256, 0, stream>>>(
      tw1, t1T, D_EXP, D_TOW);
  init_out_kernel<<<(N_TASK * B_DIM + 255) / 256, 256, 0, stream>>>(out, tb2);
  moe_expert_kernel<<<dim3(B_DIM / 256, D_EXP / 256), 512, 0, stream>>>(
      xh, ewT, expb, gates, shh);
  moe_tower_kernel<<<dim3(B_DIM / 256, N_TASK * (D_TOW / 256)), 512, 0, stream>>>(
      shh, t1T, tb1, tw2, out);
}

// Round 5
// 416.104 us; speedup vs baseline: 1.0786x; 1.0786x over previous
//
#include <hip/hip_runtime.h>
#include <hip/hip_bf16.h>

#define B_DIM   16384
#define D_IN    1024
#define D_EXP   1024
#define D_TOW   512
#define N_EXPT  8
#define N_TASK  4

typedef _Float16 f16x8 __attribute__((ext_vector_type(8)));
typedef _Float16 f16x4 __attribute__((ext_vector_type(4)));
typedef float    f32x4 __attribute__((ext_vector_type(4)));

// ---------------- async global->LDS (16B per lane, wave-uniform LDS base) ---
__device__ __forceinline__ void gll16(const void* g, void* l) {
  __builtin_amdgcn_global_load_lds(
      (const __attribute__((address_space(1))) unsigned int*)g,
      (__attribute__((address_space(3))) unsigned int*)l,
      16, 0, 0);
}

// Fragment read from a swizzled [128][64] f16 LDS half-tile.
// 16B chunk s within a 128B row holds global chunk s^(row&7).
__device__ __forceinline__ f16x8 ldfrag(const _Float16* sM, int rowbase, int ks, int lane) {
  int rl = rowbase + (lane & 15);
  int ch = ((ks << 2) + (lane >> 4)) ^ (rl & 7);
  return *(const f16x8*)&sM[rl * 64 + ch * 8];
}

// ---------------- prep: x -> f16, gates = x @ gate_w (fp32) ----------------
__global__ __launch_bounds__(256) void prep_x_kernel(
    const float* __restrict__ x, const float* __restrict__ gw,
    _Float16* __restrict__ xh, float* __restrict__ gates)
{
  __shared__ float sred[4][8];
  const int t = threadIdx.x;
  const long row = blockIdx.x;
  float4 v = ((const float4*)(x + row * D_IN))[t];
  f16x4 h;
  h[0] = (_Float16)v.x; h[1] = (_Float16)v.y; h[2] = (_Float16)v.z; h[3] = (_Float16)v.w;
  ((f16x4*)(xh + row * D_IN))[t] = h;

  float g[8];
#pragma unroll
  for (int e = 0; e < 8; ++e) g[e] = 0.f;
  const float* wp = gw + (size_t)t * 4 * 8;
  float xs[4] = {v.x, v.y, v.z, v.w};
#pragma unroll
  for (int j = 0; j < 4; ++j)
#pragma unroll
    for (int e = 0; e < 8; ++e) g[e] += xs[j] * wp[j * 8 + e];

#pragma unroll
  for (int e = 0; e < 8; ++e) {
    g[e] += __shfl_xor(g[e], 1);  g[e] += __shfl_xor(g[e], 2);
    g[e] += __shfl_xor(g[e], 4);  g[e] += __shfl_xor(g[e], 8);
    g[e] += __shfl_xor(g[e], 16); g[e] += __shfl_xor(g[e], 32);
  }
  if ((t & 63) == 0) {
#pragma unroll
    for (int e = 0; e < 8; ++e) sred[t >> 6][e] = g[e];
  }
  __syncthreads();
  if (t < 8) gates[row * 8 + t] = sred[0][t] + sred[1][t] + sred[2][t] + sred[3][t];
}

// ---------------- tiled transpose + fp32->f16: in[s][K][N] -> out[s][N][K] --
__global__ __launch_bounds__(256) void transpose_cvt_kernel(
    const float* __restrict__ in, _Float16* __restrict__ outp, int K, int N)
{
  __shared__ float tile[64][65];
  const int t = threadIdx.x;
  const int tx = t & 63, ty = t >> 6;
  const int n0 = blockIdx.x * 64;
  const int k0 = blockIdx.y * 64;
  const long s = blockIdx.z;
  const float* ip = in + s * (long)K * N;
  _Float16* op = outp + s * (long)K * N;
#pragma unroll
  for (int i = 0; i < 16; ++i) {
    int r = ty * 16 + i;
    tile[r][tx] = ip[(long)(k0 + r) * N + n0 + tx];
  }
  __syncthreads();
#pragma unroll
  for (int i = 0; i < 16; ++i) {
    int r = ty * 16 + i;
    op[(long)(n0 + r) * K + k0 + tx] = (_Float16)tile[tx][r];
  }
}

// ---------------- init d_out with tb2 --------------------------------------
__global__ void init_out_kernel(float* __restrict__ out, const float* __restrict__ tb2) {
  int i = blockIdx.x * 256 + threadIdx.x;
  if (i < N_TASK * B_DIM) out[i] = tb2[i >> 14];
}

// ============ K-tile body: 24 ds_reads + 64 MFMA, compiler-scheduled ========
// BM=256, BN=256, BK=64; 8 waves 2M x 4N; per-wave C = 128x64.
// One K-tile: entry barrier (slot ready) -> reads+MFMA (no forced waits;
// compiler inserts counted lgkmcnt) -> barrier -> stage kt+2 into this slot.
#define KTILE_COMPUTE(CUR)                                                     \
  do {                                                                         \
    const _Float16* sA = &sT[CUR][wm * 8192];                                  \
    const _Float16* sB = &sT[CUR][16384 + (wn >> 1) * 8192];                   \
    f16x8 bf[4][2];                                                            \
    _Pragma("unroll") for (int nf = 0; nf < 4; ++nf)                           \
      _Pragma("unroll") for (int ks = 0; ks < 2; ++ks)                         \
        bf[nf][ks] = ldfrag(sB, (wn & 1) * 64 + nf * 16, ks, lane);            \
    _Pragma("unroll") for (int Q = 0; Q < 4; ++Q) {                            \
      f16x8 af[2][2];                                                          \
      _Pragma("unroll") for (int m2 = 0; m2 < 2; ++m2)                         \
        _Pragma("unroll") for (int ks = 0; ks < 2; ++ks)                       \
          af[m2][ks] = ldfrag(sA, (Q * 2 + m2) * 16, ks, lane);                \
      _Pragma("unroll") for (int m2 = 0; m2 < 2; ++m2)                         \
        _Pragma("unroll") for (int nf = 0; nf < 4; ++nf)                       \
          _Pragma("unroll") for (int ks = 0; ks < 2; ++ks)                     \
            acc[Q * 2 + m2][nf] = __builtin_amdgcn_mfma_f32_16x16x32_f16(      \
                af[m2][ks], bf[nf][ks], acc[Q * 2 + m2][nf], 0, 0, 0);         \
    }                                                                          \
  } while (0)

#define FENCE asm volatile("" ::: "memory")

// ---------------- fused experts + gate-weighted combine ---------------------
// shared[b,d] = sum_e gates[b,e] * relu(x[b,:] @ exp_w[e,:,d] + exp_b[e,d])
__global__ __launch_bounds__(512, 2) void moe_expert_kernel(
    const _Float16* __restrict__ xh,    // [B,1024]
    const _Float16* __restrict__ ewT,   // [8][n=1024][k=1024]
    const float* __restrict__ expb,     // [8][1024]
    const float* __restrict__ gates,    // [B][8]
    _Float16* __restrict__ shout)       // [B,1024] f16
{
  __shared__ alignas(16) _Float16 sT[2][32768];   // 128KB
  __shared__ float sG[256 * 8];                   // 8KB
  __shared__ _Float16 sBiasH[8 * 256];            // 4KB
  const int t = threadIdx.x;
  const int lane = t & 63;
  const int wave = t >> 6;
  const int wm = wave >> 2, wn = wave & 3;

  // XCD-grouping swizzle: blocks sharing a B-panel (same by) sit on 2 XCDs.
  const int h = blockIdx.x;                 // 256 blocks
  const int bx = 2 * (h >> 3) + (h & 1);    // 0..63
  const int by = (h & 7) >> 1;              // 0..3
  const long row0 = (long)bx * 256;
  const int col0 = by * 256;

  for (int i = t; i < 256 * 8; i += 512) sG[i] = gates[row0 * 8 + i];
  for (int i = t; i < 8 * 256; i += 512)
    sBiasH[i] = (_Float16)expb[(i >> 8) * D_EXP + col0 + (i & 255)];

  const int so_t = (((t & 7) ^ ((t >> 3) & 7)) << 4);
  const char* aBase = (const char*)xh + row0 * 2048 + (size_t)(t >> 3) * 2048 + so_t;
  const char* bRoot = (const char*)ewT + (size_t)col0 * 2048 + (size_t)(t >> 3) * 2048 + so_t;
  char* sTB = (char*)&sT[0][0];

  auto SA = [&](int s, int hh, int kt) {
    const char* g = aBase + (size_t)hh * 262144 + (size_t)(kt & 15) * 128;
    char* d = sTB + s * 65536 + hh * 16384 + t * 16;
    gll16(g, d); gll16(g + 131072, d + 8192);
    FENCE;
  };
  auto SB = [&](int s, int hh, int kt) {
    const char* g = bRoot + (size_t)(kt >> 4) * 2097152 + (size_t)hh * 262144
                    + (size_t)(kt & 15) * 128;
    char* d = sTB + s * 65536 + 32768 + hh * 16384 + t * 16;
    gll16(g, d); gll16(g + 131072, d + 8192);
    FENCE;
  };

  __syncthreads();   // sG/sBias visible; vmcnt fully drained -> clean FIFO

  // prologue: kt0 -> slot0 (8 loads), kt1 -> slot1 (8 loads)
  SA(0, 0, 0); SA(0, 1, 0); SB(0, 0, 0); SB(0, 1, 0);
  SA(1, 0, 1); SA(1, 1, 1); SB(1, 0, 1); SB(1, 1, 1);
  asm volatile("s_waitcnt vmcnt(8)" ::: "memory");
  __builtin_amdgcn_s_barrier();
  FENCE;

  f32x4 acc[8][4] = {};
  f16x4 shacc[8][4] = {};

  for (int kt = 0; kt < 128; ++kt) {
    const int cur = kt & 1;

    KTILE_COMPUTE(cur);

    FENCE;
    __builtin_amdgcn_s_barrier();   // all waves done reading slot cur
    FENCE;

    if (kt < 126) {                 // stage kt+2 into slot cur (now safe)
      SA(cur, 0, kt + 2); SA(cur, 1, kt + 2);
      SB(cur, 0, kt + 2); SB(cur, 1, kt + 2);
    }

    if ((kt & 15) == 15) {          // expert boundary: relu+bias+gate combine
      const int e = kt >> 4;
      float bias4[4];
#pragma unroll
      for (int nf = 0; nf < 4; ++nf)
        bias4[nf] = (float)sBiasH[e * 256 + wn * 64 + nf * 16 + (lane & 15)];
#pragma unroll
      for (int mf = 0; mf < 8; ++mf) {
        int rbase = wm * 128 + mf * 16 + ((lane >> 4) << 2);
        float gv[4];
#pragma unroll
        for (int r = 0; r < 4; ++r) gv[r] = sG[(rbase + r) * 8 + e];
#pragma unroll
        for (int nf = 0; nf < 4; ++nf) {
          f16x4 sh = shacc[mf][nf];
#pragma unroll
          for (int r = 0; r < 4; ++r) {
            float hv = acc[mf][nf][r] + bias4[nf];
            hv = hv > 0.f ? hv : 0.f;
            sh[r] += (_Float16)(gv[r] * hv);
          }
          shacc[mf][nf] = sh;
          acc[mf][nf] = f32x4{0.f, 0.f, 0.f, 0.f};
        }
      }
    }

    if (kt < 127) {                 // wait for next slot's data, re-sync
      if (kt < 126) { asm volatile("s_waitcnt vmcnt(8)" ::: "memory"); }
      else          { asm volatile("s_waitcnt vmcnt(0)" ::: "memory"); }
      __builtin_amdgcn_s_barrier();
      FENCE;
    }
  }

  // write shared tile as f16
#pragma unroll
  for (int mf = 0; mf < 8; ++mf)
#pragma unroll
    for (int r = 0; r < 4; ++r) {
      long row = row0 + wm * 128 + mf * 16 + ((lane >> 4) << 2) + r;
      _Float16* op = shout + row * D_EXP + col0 + wn * 64 + (lane & 15);
#pragma unroll
      for (int nf = 0; nf < 4; ++nf) op[nf * 16] = shacc[mf][nf][r];
    }
}

// ---------------- fused towers ----------------------------------------------
// out[task,b] += sum_h relu(shared[b,:] @ tw1[task,:,h] + tb1[task,h]) * tw2[task,h]
__global__ __launch_bounds__(512, 2) void moe_tower_kernel(
    const _Float16* __restrict__ sh,    // [B,1024] f16
    const _Float16* __restrict__ t1T,   // [4][h=512][d=1024] f16
    const float* __restrict__ tb1,      // [4][512]
    const float* __restrict__ tw2,      // [4][512]
    float* __restrict__ out)            // [4][B]
{
  __shared__ alignas(16) _Float16 sT[2][32768];   // 128KB
  const int t = threadIdx.x;
  const int lane = t & 63;
  const int wave = t >> 6;
  const int wm = wave >> 2, wn = wave & 3;

  // swizzle: same (task, col-half) on same XCD -> B panel L2-hot
  const int h = blockIdx.x;                 // 512 blocks
  const int by = h & 7;                     // 0..7
  const int bx = h >> 3;                    // 0..63
  const long row0 = (long)bx * 256;
  const int task = by >> 1;
  const int col0 = (by & 1) * 256;

  float b1[4], w2[4];
#pragma unroll
  for (int nf = 0; nf < 4; ++nf) {
    int col = col0 + wn * 64 + nf * 16 + (lane & 15);
    b1[nf] = tb1[task * D_TOW + col];
    w2[nf] = tw2[task * D_TOW + col];
  }
  asm volatile("s_waitcnt vmcnt(0)" ::: "memory");  // clean FIFO before staging

  const int so_t = (((t & 7) ^ ((t >> 3) & 7)) << 4);
  const char* aBase = (const char*)sh + row0 * 2048 + (size_t)(t >> 3) * 2048 + so_t;
  const char* bRoot = (const char*)t1T + (size_t)task * (D_TOW * D_EXP * 2)
                      + (size_t)col0 * 2048 + (size_t)(t >> 3) * 2048 + so_t;
  char* sTB = (char*)&sT[0][0];

  auto SA = [&](int s, int hh, int kt) {
    const char* g = aBase + (size_t)hh * 262144 + (size_t)kt * 128;
    char* d = sTB + s * 65536 + hh * 16384 + t * 16;
    gll16(g, d); gll16(g + 131072, d + 8192);
    FENCE;
  };
  auto SB = [&](int s, int hh, int kt) {
    const char* g = bRoot + (size_t)hh * 262144 + (size_t)kt * 128;
    char* d = sTB + s * 65536 + 32768 + hh * 16384 + t * 16;
    gll16(g, d); gll16(g + 131072, d + 8192);
    FENCE;
  };

  __syncthreads();

  SA(0, 0, 0); SA(0, 1, 0); SB(0, 0, 0); SB(0, 1, 0);
  SA(1, 0, 1); SA(1, 1, 1); SB(1, 0, 1); SB(1, 1, 1);
  asm volatile("s_waitcnt vmcnt(8)" ::: "memory");
  __builtin_amdgcn_s_barrier();
  FENCE;

  f32x4 acc[8][4] = {};

  for (int kt = 0; kt < 16; ++kt) {
    const int cur = kt & 1;

    KTILE_COMPUTE(cur);

    FENCE;
    __builtin_amdgcn_s_barrier();
    FENCE;

    if (kt < 14) {
      SA(cur, 0, kt + 2); SA(cur, 1, kt + 2);
      SB(cur, 0, kt + 2); SB(cur, 1, kt + 2);
    }

    if (kt < 15) {
      if (kt < 14) { asm volatile("s_waitcnt vmcnt(8)" ::: "memory"); }
      else         { asm volatile("s_waitcnt vmcnt(0)" ::: "memory"); }
      __builtin_amdgcn_s_barrier();
      FENCE;
    }
  }

#pragma unroll
  for (int mf = 0; mf < 8; ++mf)
#pragma unroll
    for (int r = 0; r < 4; ++r) {
      float ssum = 0.f;
#pragma unroll
      for (int nf = 0; nf < 4; ++nf) {
        float v = acc[mf][nf][r] + b1[nf];
        v = v > 0.f ? v : 0.f;
        ssum += v * w2[nf];
      }
      ssum += __shfl_xor(ssum, 1);
      ssum += __shfl_xor(ssum, 2);
      ssum += __shfl_xor(ssum, 4);
      ssum += __shfl_xor(ssum, 8);
      if ((lane & 15) == 0) {
        long row = row0 + wm * 128 + mf * 16 + ((lane >> 4) << 2) + r;
        atomicAdd(&out[(size_t)task * B_DIM + row], ssum);
      }
    }
}

// ---------------- launch -----------------------------------------------------
extern "C" void kernel_launch(void* const* d_in, const int* in_sizes, int n_in,
                              void* d_out, int out_size, void* d_ws, size_t ws_size,
                              hipStream_t stream) {
  const float* x    = (const float*)d_in[0];
  const float* gw   = (const float*)d_in[1];
  const float* expw = (const float*)d_in[2];
  const float* expb = (const float*)d_in[3];
  const float* tw1  = (const float*)d_in[4];
  const float* tb1  = (const float*)d_in[5];
  const float* tw2  = (const float*)d_in[6];
  const float* tb2  = (const float*)d_in[7];
  float* out = (float*)d_out;

  char* ws = (char*)d_ws;
  _Float16* xh  = (_Float16*)ws;  ws += (size_t)B_DIM * D_IN * 2;          // 32 MB
  _Float16* ewT = (_Float16*)ws;  ws += (size_t)N_EXPT * D_IN * D_EXP * 2; // 16 MB
  _Float16* t1T = (_Float16*)ws;  ws += (size_t)N_TASK * D_TOW * D_EXP * 2; // 4 MB
  _Float16* shh = (_Float16*)ws;  ws += (size_t)B_DIM * D_EXP * 2;         // 32 MB
  float* gates  = (float*)ws;     ws += (size_t)B_DIM * N_EXPT * 4;        // 0.5 MB

  prep_x_kernel<<<B_DIM, 256, 0, stream>>>(x, gw, xh, gates);
  transpose_cvt_kernel<<<dim3(D_EXP / 64, D_IN / 64, N_EXPT), 256, 0, stream>>>(
      expw, ewT, D_IN, D_EXP);
  transpose_cvt_kernel<<<dim3(D_TOW / 64, D_EXP / 64, N_TASK), 256, 0, stream>>>(
      tw1, t1T, D_EXP, D_TOW);
  init_out_kernel<<<(N_TASK * B_DIM + 255) / 256, 256, 0, stream>>>(out, tb2);
  moe_expert_kernel<<<256, 512, 0, stream>>>(xh, ewT, expb, gates, shh);
  moe_tower_kernel<<<512, 512, 0, stream>>>(shh, t1T, tb1, tw2, out);
}